// Round 9
// baseline (364.148 us; speedup 1.0000x reference)
//
#include <hip/hip_runtime.h>
#include <hip/hip_bf16.h>
#include <math.h>

typedef __bf16 bf16_t;
typedef __attribute__((ext_vector_type(8))) __bf16 bf16x8;
typedef __attribute__((ext_vector_type(4))) float f32x4;

constexpr int B_ = 2, S_ = 4096, D_ = 512;
constexpr int BS_ = B_ * S_;
constexpr int NT_ = 256;
constexpr long QKV_E  = (long)BS_ * D_;          // 4 Mi elems
constexpr long W_E    = (long)D_ * D_;           // 256 Ki elems (2^18)
constexpr long CVT_UNITS = (QKV_E + 4 * W_E) / 4;    // 1,310,720
constexpr float SCALE_ = 0.044194173824159216f;      // 1/sqrt(512)

// Async global->LDS 16B copy. LDS dest must be wave-uniform base + lane*16.
__device__ __forceinline__ void load16_lds(const bf16_t* g, bf16_t* l) {
    __builtin_amdgcn_global_load_lds(
        (const __attribute__((address_space(1))) void*)g,
        (__attribute__((address_space(3))) void*)l, 16, 0, 0);
}

// Bijective XCD swizzle (nwg % 8 == 0): each XCD gets a CONTIGUOUS chunk of
// the tile space -> neighboring tiles (sharing operand panels) hit one L2.
__device__ __forceinline__ int swz8(int bid, int chunk) {
    return (bid & 7) * chunk + (bid >> 3);
}

// ---------------------------------------------------------------------------
// Streaming: fp32->bf16 of x + 4 weights into contiguous Xc|Wq|Wk|Wv|Wo.
// ---------------------------------------------------------------------------
__device__ __forceinline__ void dev_cvt(long u,
    const float* x, const float* Wq, const float* Wk, const float* Wv,
    const float* Wo, bf16_t* dst)
{
    const long i = u * 4;
    const float* src; long o;
    if (i < QKV_E) { src = x; o = i; }
    else {
        const long j = i - QKV_E;
        const int w = (int)(j >> 18);
        o = j & (W_E - 1);
        src = (w == 0) ? Wq : (w == 1) ? Wk : (w == 2) ? Wv : Wo;
    }
    const float4 v = *(const float4*)(src + o);
    bf16_t out[4] = {(bf16_t)v.x, (bf16_t)v.y, (bf16_t)v.z, (bf16_t)v.w};
    *(uint2*)(dst + i) = *(uint2*)out;
}

// ---------------------------------------------------------------------------
// 128x128 tile GEMM K-loop, BK=64. LDS [128 rows][64 cols] bf16 per matrix.
// Linear gload_lds dest; XOR swizzle on the GLOBAL source col-group and on
// the read address (both-sides, rule 21). b128 reads at structural minimum.
// ---------------------------------------------------------------------------
__device__ __forceinline__ void kloop64(
    const bf16_t* At, const bf16_t* Bt, long ldA, long ldB, int kSteps,
    bf16_t* As, bf16_t* Bs, int tid, int wr, int wc, int quad, int r16,
    f32x4 (&acc)[4][4])
{
    const int srow = tid >> 3;                        // 0..31
    const int cg = ((tid & 7) ^ (srow & 7)) * 8;      // pre-swizzled src col
    const bf16_t* gA = At + (long)srow * ldA + cg;
    const bf16_t* gB = Bt + (long)srow * ldB + cg;
    bf16_t* lA = As + tid * 8;
    bf16_t* lB = Bs + tid * 8;

    for (int s = 0; s < kSteps; s++) {
        const int k0 = s * 64;
#pragma unroll
        for (int rr = 0; rr < 4; rr++) {
            load16_lds(gA + (long)rr * 32 * ldA + k0, lA + rr * 2048);
            load16_lds(gB + (long)rr * 32 * ldB + k0, lB + rr * 2048);
        }
        __syncthreads();
#pragma unroll
        for (int kh = 0; kh < 2; kh++) {
            bf16x8 af[4], bfr[4];
#pragma unroll
            for (int i = 0; i < 4; i++) {
                const int row = wr * 64 + i * 16 + r16;
                af[i] = *(const bf16x8*)(As + row * 64 +
                        (((kh << 2) + quad) ^ (row & 7)) * 8);
            }
#pragma unroll
            for (int j = 0; j < 4; j++) {
                const int row = wc * 64 + j * 16 + r16;
                bfr[j] = *(const bf16x8*)(Bs + row * 64 +
                        (((kh << 2) + quad) ^ (row & 7)) * 8);
            }
#pragma unroll
            for (int i = 0; i < 4; i++)
#pragma unroll
                for (int j = 0; j < 4; j++)
                    acc[i][j] = __builtin_amdgcn_mfma_f32_16x16x32_bf16(
                        af[i], bfr[j], acc[i][j], 0, 0, 0);
        }
        __syncthreads();
    }
}

// ---------------------------------------------------------------------------
// QKV + direct-V^T projections (sel 2 swaps operands: C[d][s] = V^T).
// ---------------------------------------------------------------------------
__device__ __forceinline__ void dev_qkv_tile(int t,
    const bf16_t* Xc, const bf16_t* Wqc, const bf16_t* Wkc, const bf16_t* Wvc,
    const float* bq, const float* bk, const float* bv,
    bf16_t* Q, bf16_t* Kp, bf16_t* VT, char* smem, int tid)
{
    constexpr int K = 512;
    const int sel = t >> 8;          // 0:Q 1:K 2:VT
    const int tt  = t & 255;

    bf16_t* As = (bf16_t*)smem;
    bf16_t* Bs = As + 128 * 64;
    const int wave = tid >> 6, lane = tid & 63;
    const int quad = lane >> 4, r16 = lane & 15;
    const int wr = wave >> 1, wc = wave & 1;

    f32x4 acc[4][4] = {};

    if (sel < 2) {
        const int m0 = (tt >> 2) * 128;          // X row tile (8192)
        const int n0 = (tt & 3) * 128;           // out-feature tile (512)
        const bf16_t* Bw = sel ? Wkc : Wqc;
        const float* bias = sel ? bk : bq;
        bf16_t* C = sel ? Kp : Q;
        kloop64(Xc + (long)m0 * K, Bw + (long)n0 * K, K, K, K / 64,
                As, Bs, tid, wr, wc, quad, r16, acc);
#pragma unroll
        for (int i = 0; i < 4; i++)
#pragma unroll
            for (int j = 0; j < 4; j++) {
                const int gn = n0 + wc * 64 + j * 16 + r16;
                const float bval = bias[gn];
#pragma unroll
                for (int reg = 0; reg < 4; reg++) {
                    const int gm = m0 + wr * 64 + i * 16 + quad * 4 + reg;
                    C[(long)gm * 512 + gn] = (bf16_t)(acc[i][j][reg] + bval);
                }
            }
    } else {
        const int m0 = (tt & 3) * 128;           // d tile (512)
        const int n0 = (tt >> 2) * 128;          // X row tile (8192)
        kloop64(Wvc + (long)m0 * K, Xc + (long)n0 * K, K, K, K / 64,
                As, Bs, tid, wr, wc, quad, r16, acc);
#pragma unroll
        for (int i = 0; i < 4; i++)
#pragma unroll
            for (int j = 0; j < 4; j++) {
                const int gn = n0 + wc * 64 + j * 16 + r16;   // global s-index
                const int b = gn >> 12, q = gn & 4095;
#pragma unroll
                for (int reg = 0; reg < 4; reg++) {
                    const int gm = m0 + wr * 64 + i * 16 + quad * 4 + reg; // d
                    VT[(long)b * D_ * S_ + (long)gm * S_ + q] =
                        (bf16_t)(acc[i][j][reg] + bv[gm]);
                }
            }
    }
}

// ---------------------------------------------------------------------------
// Scores: SC[q][k] = keep ? exp(scale*(Q.K)) : 0 (bf16), rowsum atomics.
// Mask is PRELOADED into a per-thread 64-bit register bitmask BEFORE the
// kloop (loads overlap staging; removes the epilogue's dependent global-load
// chain). Epilogue is barrier-free: wlds is per-wave (kloop's final barrier
// already fences As/Bs; per-wave LDS ordering is handled by lgkmcnt).
// ---------------------------------------------------------------------------
__device__ __forceinline__ void dev_scores_tile(int t,
    const bf16_t* Q, const bf16_t* Kp, const float* mask,
    bf16_t* SC, float* rowsum, char* smem, int tid)
{
    constexpr int S = S_, K = D_;
    const int x = t & 31;
    const int y = (t >> 5) & 31;
    const int b = t >> 10;
    const int m0 = y * 128, n0 = x * 128;

    bf16_t* As = (bf16_t*)smem;
    bf16_t* Bs = As + 128 * 64;
    const int wave = tid >> 6, lane = tid & 63;
    const int quad = lane >> 4, r16 = lane & 15;
    const int wr = wave >> 1, wc = wave & 1;

    const int erow = lane >> 2;                 // epilogue row within 16
    const int ecg  = lane & 3;                  // epilogue 16-col group
    const long mbase = (long)b * S * S;
    const int egn = n0 + wc * 64 + ecg * 16;

    // ---- mask -> 64-bit register bitmask (bit = i*16 + c*4 + w) ----
    unsigned long long mbits = 0ull;
#pragma unroll
    for (int i = 0; i < 4; i++) {
        const int gm = m0 + wr * 64 + i * 16 + erow;
        const float* mp = mask + mbase + (long)gm * S + egn;
#pragma unroll
        for (int c = 0; c < 4; c++) {
            const float4 mk = *(const float4*)(mp + c * 4);
            mbits |= (unsigned long long)(mk.x > 0.95f) << (i * 16 + c * 4 + 0);
            mbits |= (unsigned long long)(mk.y > 0.95f) << (i * 16 + c * 4 + 1);
            mbits |= (unsigned long long)(mk.z > 0.95f) << (i * 16 + c * 4 + 2);
            mbits |= (unsigned long long)(mk.w > 0.95f) << (i * 16 + c * 4 + 3);
        }
    }

    f32x4 acc[4][4] = {};
    kloop64(Q + (long)b * S * K + (long)m0 * K,
            Kp + (long)b * S * K + (long)n0 * K, K, K, K / 64,
            As, Bs, tid, wr, wc, quad, r16, acc);

    float* wlds = (float*)smem + wave * 1088;   // 16 rows x 68 cols fp32 (pad)

#pragma unroll
    for (int i = 0; i < 4; i++) {
#pragma unroll
        for (int j = 0; j < 4; j++)
#pragma unroll
            for (int reg = 0; reg < 4; reg++)
                wlds[(quad * 4 + reg) * 68 + j * 16 + r16] = acc[i][j][reg];
        // no __syncthreads: wlds is private to this wave; lgkmcnt orders

        float v[16];
#pragma unroll
        for (int c = 0; c < 4; c++) {
            const float4 tv = *(const float4*)(wlds + erow * 68 + ecg * 16 + c * 4);
            v[c * 4 + 0] = tv.x; v[c * 4 + 1] = tv.y;
            v[c * 4 + 2] = tv.z; v[c * 4 + 3] = tv.w;
        }

        const int gm = m0 + wr * 64 + i * 16 + erow;
        const unsigned mi = (unsigned)(mbits >> (i * 16)) & 0xFFFFu;

        float e[16];
#pragma unroll
        for (int tt = 0; tt < 16; tt++)
            e[tt] = (mi & (1u << tt)) ? __expf(v[tt] * SCALE_) : 0.f;

        bf16x8 o0, o1;
        float rsum = 0.f;
#pragma unroll
        for (int tt = 0; tt < 8; tt++) {
            rsum += e[tt] + e[tt + 8];
            o0[tt] = (bf16_t)e[tt];
            o1[tt] = (bf16_t)e[tt + 8];
        }
        bf16_t* cp = SC + mbase + (long)gm * S + egn;
        *(bf16x8*)cp       = o0;
        *(bf16x8*)(cp + 8) = o1;

        rsum += __shfl_xor(rsum, 1, 64);
        rsum += __shfl_xor(rsum, 2, 64);
        if (ecg == 0) atomicAdd(&rowsum[b * S + gm], rsum);
    }
}

// ---------------------------------------------------------------------------
// PV split-K (KS=4), normalized bf16 partials [ks][b][d][q].
// ---------------------------------------------------------------------------
__device__ __forceinline__ void dev_pv_tile(int t,
    const bf16_t* VT, const bf16_t* SC, const float* rowsum,
    bf16_t* part, char* smem, int tid)
{
    constexpr int S = S_, D = D_;
    constexpr int KC = S / 4;                   // 1024
    const int x = t & 31;                       // q tile
    const int y = (t >> 5) & 3;                 // d tile
    const int z = t >> 7;                       // 0..7 = b*4+ks
    const int b = z >> 2, ks = z & 3;
    const int m0 = y * 128, n0 = x * 128;
    const int kbeg = ks * KC;

    bf16_t* As = (bf16_t*)smem;
    bf16_t* Bs = As + 128 * 64;
    const int wave = tid >> 6, lane = tid & 63;
    const int quad = lane >> 4, r16 = lane & 15;
    const int wr = wave >> 1, wc = wave & 1;

    f32x4 acc[4][4] = {};
    kloop64(VT + (long)b * D * S + (long)m0 * S + kbeg,
            SC + (long)b * S * S + (long)n0 * S + kbeg, S, S, KC / 64,
            As, Bs, tid, wr, wc, quad, r16, acc);

    const long obase = ((long)ks * B_ + b) * (long)D * S;
#pragma unroll
    for (int i = 0; i < 4; i++)
#pragma unroll
        for (int j = 0; j < 4; j++) {
            const int gn = n0 + wc * 64 + j * 16 + r16;
            const float inv = 1.f / rowsum[b * S + gn];
#pragma unroll
            for (int reg = 0; reg < 4; reg++) {
                const int gm = m0 + wr * 64 + i * 16 + quad * 4 + reg;
                part[obase + (long)gm * S + gn] = (bf16_t)(acc[i][j][reg] * inv);
            }
        }
}

// ---------------------------------------------------------------------------
// Out projection with INLINE 4-way partial reduction (A = sum of 4 normalized
// bf16 partials, reg-staged + swizzled ds_write; B = Wo via gload_lds).
// Reference view() trick: part's flat [ks][b*D*S] layout IS the reshaped
// [BS][D] A-matrix (torch .transpose(1,2).view(B,S,D) is a reinterpret).
// ---------------------------------------------------------------------------
__device__ __forceinline__ void dev_out_tile(int t,
    const bf16_t* part, const bf16_t* Woc, const float* bo, float* C,
    char* smem, int tid)
{
    constexpr int N = 512, K = 512;
    const int m0 = (t >> 2) * 128, n0 = (t & 3) * 128;

    bf16_t* As = (bf16_t*)smem;
    bf16_t* Bs = As + 128 * 64;
    const int wave = tid >> 6, lane = tid & 63;
    const int quad = lane >> 4, r16 = lane & 15;
    const int wr = wave >> 1, wc = wave & 1;

    const int srow = tid >> 3;
    const int cg = ((tid & 7) ^ (srow & 7)) * 8;
    const bf16_t* gA0 = part + (long)(m0 + srow) * K + cg;
    const bf16_t* gB  = Woc + (long)(n0 + srow) * K + cg;
    bf16_t* lA = As + tid * 8;
    bf16_t* lB = Bs + tid * 8;

    f32x4 acc[4][4] = {};

    for (int s = 0; s < K / 64; s++) {
        const int k0 = s * 64;
#pragma unroll
        for (int rr = 0; rr < 4; rr++) {
            const bf16x8 a0 = *(const bf16x8*)(gA0 + (long)rr * 32 * K + k0);
            const bf16x8 a1 = *(const bf16x8*)(gA0 + QKV_E + (long)rr * 32 * K + k0);
            const bf16x8 a2 = *(const bf16x8*)(gA0 + 2 * QKV_E + (long)rr * 32 * K + k0);
            const bf16x8 a3 = *(const bf16x8*)(gA0 + 3 * QKV_E + (long)rr * 32 * K + k0);
            bf16x8 sm;
#pragma unroll
            for (int e = 0; e < 8; e++)
                sm[e] = (bf16_t)((float)a0[e] + (float)a1[e] +
                                 (float)a2[e] + (float)a3[e]);
            *(bf16x8*)(lA + rr * 2048) = sm;
            load16_lds(gB + (long)rr * 32 * K + k0, lB + rr * 2048);
        }
        __syncthreads();
#pragma unroll
        for (int kh = 0; kh < 2; kh++) {
            bf16x8 af[4], bfr[4];
#pragma unroll
            for (int i = 0; i < 4; i++) {
                const int row = wr * 64 + i * 16 + r16;
                af[i] = *(const bf16x8*)(As + row * 64 +
                        (((kh << 2) + quad) ^ (row & 7)) * 8);
            }
#pragma unroll
            for (int j = 0; j < 4; j++) {
                const int row = wc * 64 + j * 16 + r16;
                bfr[j] = *(const bf16x8*)(Bs + row * 64 +
                        (((kh << 2) + quad) ^ (row & 7)) * 8);
            }
#pragma unroll
            for (int i = 0; i < 4; i++)
#pragma unroll
                for (int j = 0; j < 4; j++)
                    acc[i][j] = __builtin_amdgcn_mfma_f32_16x16x32_bf16(
                        af[i], bfr[j], acc[i][j], 0, 0, 0);
        }
        __syncthreads();
    }

#pragma unroll
    for (int i = 0; i < 4; i++)
#pragma unroll
        for (int j = 0; j < 4; j++) {
            const int gn = n0 + wc * 64 + j * 16 + r16;
            const float bval = bo[gn];
#pragma unroll
            for (int reg = 0; reg < 4; reg++) {
                const int gm = m0 + wr * 64 + i * 16 + quad * 4 + reg;
                C[(long)gm * N + gn] = acc[i][j][reg] + bval;
            }
        }
}

// ---------------------------------------------------------------------------
// 5 plain launches, one tile per block + XCD-contiguous swizzle.
// ---------------------------------------------------------------------------
__global__ __launch_bounds__(256) void k_s1(
    const float* x, const float* mask, const float* Wq, const float* Wk,
    const float* Wv, const float* Wo, bf16_t* Xc, float* rowsum)
{
    const long gtid = (long)blockIdx.x * NT_ + threadIdx.x;
    for (long u = gtid; u < CVT_UNITS; u += 1280L * NT_)
        dev_cvt(u, x, Wq, Wk, Wv, Wo, Xc);
    if (gtid < BS_ / 4) {
        const float4 z = {0.f, 0.f, 0.f, 0.f};
        *(float4*)(rowsum + gtid * 4) = z;
    }
}

__global__ __launch_bounds__(256) void k_s2(
    const bf16_t* Xc, const float* bq, const float* bk, const float* bv,
    bf16_t* Q, bf16_t* Kp, bf16_t* VT)
{
    __shared__ char smem[32768];
    const bf16_t* Wqc = Xc + QKV_E;
    dev_qkv_tile(swz8(blockIdx.x, 96), Xc, Wqc, Wqc + W_E, Wqc + 2 * W_E,
                 bq, bk, bv, Q, Kp, VT, smem, threadIdx.x);
}

__global__ __launch_bounds__(256) void k_s3(
    const bf16_t* Q, const bf16_t* Kp, const float* mask,
    bf16_t* SC, float* rowsum)
{
    __shared__ char smem[32768];
    dev_scores_tile(swz8(blockIdx.x, 256), Q, Kp, mask, SC, rowsum,
                    smem, threadIdx.x);
}

__global__ __launch_bounds__(256) void k_s4(
    const bf16_t* VT, const bf16_t* SC, const float* rowsum, bf16_t* part)
{
    __shared__ char smem[32768];
    dev_pv_tile(swz8(blockIdx.x, 128), VT, SC, rowsum, part, smem, threadIdx.x);
}

__global__ __launch_bounds__(256) void k_s6(
    const bf16_t* part, const bf16_t* Xc, const float* bo, float* C)
{
    __shared__ char smem[32768];
    const bf16_t* Woc = Xc + QKV_E + 3 * W_E;
    dev_out_tile(swz8(blockIdx.x, 32), part, Woc, bo, C, smem, threadIdx.x);
}

// ---------------------------------------------------------------------------
extern "C" void kernel_launch(void* const* d_in, const int* in_sizes, int n_in,
                              void* d_out, int out_size, void* d_ws, size_t ws_size,
                              hipStream_t stream)
{
    const float* x    = (const float*)d_in[0];
    const float* mask = (const float*)d_in[1];
    const float* Wq   = (const float*)d_in[2];
    const float* bq   = (const float*)d_in[3];
    const float* Wk   = (const float*)d_in[4];
    const float* bk   = (const float*)d_in[5];
    const float* Wv   = (const float*)d_in[6];
    const float* bv   = (const float*)d_in[7];
    const float* Wo   = (const float*)d_in[8];
    const float* bo   = (const float*)d_in[9];
    float* outp = (float*)d_out;

    char* ws = (char*)d_ws;
    bf16_t* SC = (bf16_t*)ws;   ws += (long)BS_ * S_ * 2;          // 64 MiB
    bf16_t* VT = (bf16_t*)ws;   ws += QKV_E * 2;                   // 8
    bf16_t* Q  = (bf16_t*)ws;   ws += QKV_E * 2;                   // 8
    bf16_t* Kp = (bf16_t*)ws;   ws += QKV_E * 2;                   // 8
    bf16_t* Xc = (bf16_t*)ws;   ws += (QKV_E + 4 * W_E) * 2;       // 10 (Xc|Wq|Wk|Wv|Wo)
    bf16_t* part = (bf16_t*)ws; ws += 4 * QKV_E * 2;               // 32 (KS=4)
    float* rowsum = (float*)ws; ws += (long)BS_ * 4;               // 32 KB

    dim3 blk(NT_);
    k_s1<<<dim3(1280), blk, 0, stream>>>(x, mask, Wq, Wk, Wv, Wo, Xc, rowsum);
    k_s2<<<dim3(768),  blk, 0, stream>>>(Xc, bq, bk, bv, Q, Kp, VT);
    k_s3<<<dim3(2048), blk, 0, stream>>>(Q, Kp, mask, SC, rowsum);
    k_s4<<<dim3(1024), blk, 0, stream>>>(VT, SC, rowsum, part);
    k_s6<<<dim3(256),  blk, 0, stream>>>(part, Xc, bo, outp);
}